// Round 14
// baseline (21432.906 us; speedup 1.0000x reference)
//
#include <hip/hip_runtime.h>

typedef unsigned int uint;
typedef unsigned short ushort;
typedef __attribute__((ext_vector_type(8))) short bf16x8;
typedef __attribute__((ext_vector_type(4))) float f32x4;

#define T_STEPS 512
#define BATCH   512
#define NB      8
#define NBLK    64
#define NIT     515      // 512 + 3 skew

// U (ushort) layout
#define ZROW 0           // 128 zeros, never written
#define XPB  128         // x planes: 2 parities x (hi 832 + lo 832)
#define O0B  3456        // out0: 2 parities
#define O1B  6784        // out1: 4-slot ring
#define O2B  13440       // out2: 2 parities
#define PBB  16768       // resnet pb: 1 x (hi+lo)
#define HB   18432       // h rings: 22 slots x (hi 320 + lo 320)
#define USZ  32512
#define OSZ  1664        // per parity (hi+lo)
#define PLN  832         // one plane: 8 rows x 104
#define RS   104
#define HSL  640
#define HRS  40
#define CSZ  (22*1024 + 16)

__device__ __forceinline__ ushort f2bf(float f){
  uint u = __builtin_bit_cast(uint, f);
  u = (u + 0x7FFFu + ((u >> 16) & 1u)) >> 16;   // RNE
  return (ushort)u;
}
__device__ __forceinline__ float bf2f(ushort h){
  uint u = ((uint)h) << 16; return __builtin_bit_cast(float, u);
}
__device__ __forceinline__ float sigm(float x){
  float e = __builtin_exp2f(-1.44269504f * x);
  return __builtin_amdgcn_rcpf(1.0f + e);
}
__device__ __forceinline__ float tanh_fast(float x){
  float e = __builtin_exp2f(-2.88539008f * x);
  return 2.0f * __builtin_amdgcn_rcpf(1.0f + e) - 1.0f;
}

// All 4 layers in ONE block (64 blocks x 1024 threads, 16 waves, 4 waves/layer).
// Skewed in-block pipeline: at iteration i, layer l computes step t=i-l.
// Inter-layer data via LDS planes; NO inter-block communication anywhere.
// Weights in registers (split-bf16 hi/lo, 2 column-groups per wave).
__global__ __launch_bounds__(1024, 1)
void rnn_all(const float* __restrict__ x,
             const float* __restrict__ W0, const float* __restrict__ b0,
             const float* __restrict__ W1, const float* __restrict__ b1,
             const float* __restrict__ W2, const float* __restrict__ b2,
             const float* __restrict__ W3, const float* __restrict__ b3,
             const float* __restrict__ Wa, const float* __restrict__ ba,
             float* __restrict__ y_out)
{
  const int tid  = threadIdx.x;
  const int wv   = tid >> 6;       // 0..15
  const int lane = tid & 63;
  const int l15  = lane & 15;
  const int hi   = lane >> 4;      // 0..3
  const int layer= wv >> 2;        // 0..3
  const int sub  = wv & 3;         // 0..3
  const int rep  = blockIdx.x;     // 0..63
  const int b0r  = rep * NB;
  const bool sel8 = (l15 < 8);

  const int dil = (layer==0)?1:(layer==1)?3:(layer==2)?6:12;
  const int KIN = (layer==0)?64:96;
  const int K   = KIN + 64;
  const int nin = KIN >> 5;        // 2 or 3
  const float* Wl = (layer==0)?W0:(layer==1)?W1:(layer==2)?W2:W3;
  const float* bl = (layer==0)?b0:(layer==1)?b1:(layer==2)?b2:b3;
  const int hboff = HB + ((layer==0)?0:(layer==1)?1:(layer==2)?4:10)*HSL;
  const int cof   = ((layer==0)?0:(layer==1)?1:(layer==2)?4:10)*1024;

  __shared__ __align__(16) ushort U[USZ];
  __shared__ __align__(16) float  C[CSZ];
  __shared__ __align__(16) float  o3f[768];

  for (int i = tid; i < USZ; i += 1024) U[i] = 0;
  for (int i = tid; i < CSZ; i += 1024) C[i] = 0.0f;
  for (int i = tid; i < 768; i += 1024) o3f[i] = 0.0f;

  // ---- weights: 2 column-groups (sidx = 32*sub + 16*g + l15) ----
  bf16x8 whi[2][4][5], wlo[2][4][5];
  #pragma unroll
  for (int g = 0; g < 2; ++g){
    #pragma unroll
    for (int j = 0; j < 4; ++j){
      const int grow = 128*j + 32*sub + 16*g + l15;
      #pragma unroll
      for (int ks = 0; ks < 5; ++ks){
        bf16x8 vh, vl;
        const int cb = ks*32 + hi*8;
        if (cb < K){
          const float* p = Wl + (size_t)grow*K + cb;
          #pragma unroll
          for (int q = 0; q < 8; ++q){
            float w = p[q];
            ushort h = f2bf(w);
            vh[q] = (short)h;
            vl[q] = (short)f2bf(w - bf2f(h));
          }
        } else {
          #pragma unroll
          for (int q = 0; q < 8; ++q){ vh[q] = 0; vl[q] = 0; }
        }
        whi[g][j][ks] = vh; wlo[g][j][ks] = vl;
      }
    }
  }
  float bias[2][4];
  #pragma unroll
  for (int g = 0; g < 2; ++g)
    #pragma unroll
    for (int j = 0; j < 4; ++j) bias[g][j] = bl[128*j + 32*sub + 16*g + l15];

  // projection weights (layer-3 waves only; ocol = 16*sub + l15)
  bf16x8 phi[3], plo[3];
  #pragma unroll
  for (int ks = 0; ks < 3; ++ks){
    bf16x8 z;
    #pragma unroll
    for (int q = 0; q < 8; ++q) z[q] = 0;
    phi[ks] = z; plo[ks] = z;
  }
  float bav = 0.0f;
  const int ocol = 16*sub + l15;
  if (layer == 3){
    #pragma unroll
    for (int ks = 0; ks < 3; ++ks){
      const float* p = Wa + (size_t)ocol*96 + ks*32 + hi*8;
      bf16x8 vh, vl;
      #pragma unroll
      for (int q = 0; q < 8; ++q){
        float w = p[q];
        ushort h = f2bf(w);
        vh[q] = (short)h;
        vl[q] = (short)f2bf(w - bf2f(h));
      }
      phi[ks] = vh; plo[ks] = vl;
    }
    bav = ba[ocol];
  }

  __syncthreads();
  // ---- stage x[0] into parity 0; prefetch x[1] ----
  float xv = 0.0f;
  if (tid < 512){
    const int r = tid >> 6, c = tid & 63;
    float v = x[(size_t)(b0r + r)*64 + c];
    ushort h = f2bf(v);
    U[XPB + r*RS + c]       = h;
    U[XPB + PLN + r*RS + c] = f2bf(v - bf2f(h));
    xv = x[(size_t)(BATCH + b0r + r)*64 + c];
  }
  __syncthreads();

  int cur = 0, prv = dil - 1;
  f32x4 n0p = (f32x4){0,0,0,0}, n1p = (f32x4){0,0,0,0};

  for (int i = 0; i < NIT; ++i){
    const int t = i - layer;
    const bool act = (t >= 0) && (t < T_STEPS);
    const int del = (t >= dil) ? cur : prv;

    // ---- GEMM phase ----
    f32x4 A0[4], A1[4];
    if (act){
      const int ib = (layer==0)? XPB + (i&1)*OSZ :
                     (layer==1)? O0B + ((i-1)&1)*OSZ :
                     (layer==2)? O1B + ((i-1)&3)*OSZ :
                                 O2B + ((i-1)&1)*OSZ;
      #pragma unroll
      for (int j = 0; j < 4; ++j){
        A0[j] = (f32x4){bias[0][j],bias[0][j],bias[0][j],bias[0][j]};
        A1[j] = (f32x4){bias[1][j],bias[1][j],bias[1][j],bias[1][j]};
      }
      #pragma unroll
      for (int ks = 0; ks < 5; ++ks){
        if (ks*32 < K){
          int ih, il;
          if (ks < nin){
            const int base = sel8 ? ib + l15*RS : ZROW;
            ih = base + hi*8 + ks*32;
            il = sel8 ? ih + PLN : ih;
          } else {
            const int slot = (ks == nin) ? prv : del;
            const int base = sel8 ? hboff + slot*HSL + l15*HRS : ZROW;
            ih = base + hi*8;
            il = sel8 ? ih + 320 : ih;
          }
          bf16x8 ah = *(const bf16x8*)(U + ih);
          bf16x8 al = *(const bf16x8*)(U + il);
          #pragma unroll
          for (int j = 0; j < 4; ++j){
            A0[j] = __builtin_amdgcn_mfma_f32_16x16x32_bf16(ah, whi[0][j][ks], A0[j], 0, 0, 0);
            A0[j] = __builtin_amdgcn_mfma_f32_16x16x32_bf16(al, whi[0][j][ks], A0[j], 0, 0, 0);
            A0[j] = __builtin_amdgcn_mfma_f32_16x16x32_bf16(ah, wlo[0][j][ks], A0[j], 0, 0, 0);
            A1[j] = __builtin_amdgcn_mfma_f32_16x16x32_bf16(ah, whi[1][j][ks], A1[j], 0, 0, 0);
            A1[j] = __builtin_amdgcn_mfma_f32_16x16x32_bf16(al, whi[1][j][ks], A1[j], 0, 0, 0);
            A1[j] = __builtin_amdgcn_mfma_f32_16x16x32_bf16(ah, wlo[1][j][ks], A1[j], 0, 0, 0);
          }
        }
      }
    }
    __syncthreads();   // B1

    // ---- gates phase ----
    if (act){
      const bool has_prev = (t >= 1), has_del = (t >= dil);
      const int ob = (layer==0)? O0B + (i&1)*OSZ :
                     (layer==1)? O1B + (i&3)*OSZ :
                                 O2B + (i&1)*OSZ;   // layer3 unused
      #pragma unroll
      for (int g = 0; g < 2; ++g){
        const f32x4* A = (g == 0) ? A0 : A1;
        const f32x4 pc = (g == 0) ? n0p : n1p;
        const int sg = 32*sub + 16*g + l15;
        f32x4 dc;
        if (dil == 1) dc = pc;
        else dc = *(const f32x4*)(C + cof + del*1024 + sg*8 + (hi&1)*4);
        f32x4 ncv; float whv[4];
        #pragma unroll
        for (int k = 0; k < 4; ++k){
          float f  = sigm(A[0][k] + 1.0f);
          float cd = tanh_fast(A[1][k]);
          float al = sigm(A[2][k]);
          float og = sigm(A[3][k]);
          float wt = has_del ? (al*pc[k] + (1.0f - al)*dc[k]) : pc[k];
          float nc = has_prev ? (f*wt + (1.0f - f)*cd) : cd;
          ncv[k] = nc;
          whv[k] = og * nc;
        }
        if (hi < 2){
          *(f32x4*)(C + cof + cur*1024 + sg*8 + hi*4) = ncv;
          #pragma unroll
          for (int k = 0; k < 4; ++k){
            const int r = hi*4 + k;
            const float w = whv[k];
            if (sg < 96){
              if (layer == 3){
                o3f[r*96 + sg] = w;
              } else {
                ushort h = f2bf(w);
                U[ob + r*RS + sg]       = h;
                U[ob + PLN + r*RS + sg] = f2bf(w - bf2f(h));
              }
            } else {
              const int hb2 = hboff + cur*HSL;
              ushort h = f2bf(w);
              U[hb2 + r*HRS + (sg - 96)]       = h;
              U[hb2 + 320 + r*HRS + (sg - 96)] = f2bf(w - bf2f(h));
            }
          }
        }
        if (g == 0) n0p = ncv; else n1p = ncv;
      }
      prv = cur;
      cur = (cur + 1 == dil) ? 0 : cur + 1;
    }
    __syncthreads();   // B2

    // ---- aux phase: resnet (layer3 waves) + x staging (waves 0-7) ----
    const bool l3act = (i >= 3) && (i < T_STEPS + 3);
    if (layer == 3 && l3act){
      const int o1b = O1B + ((i-2)&3)*OSZ;
      for (int j = tid - 768; j < 768; j += 256){
        const int r = j / 96, c2 = j % 96;
        float v = o3f[j] + bf2f(U[o1b + r*RS + c2]) + bf2f(U[o1b + PLN + r*RS + c2]);
        ushort h = f2bf(v);
        U[PBB + r*RS + c2]       = h;
        U[PBB + PLN + r*RS + c2] = f2bf(v - bf2f(h));
      }
    }
    if (tid < 512 && (i + 1) < T_STEPS){
      const int r = tid >> 6, c2 = tid & 63;
      const int xb = XPB + ((i+1)&1)*OSZ;
      ushort h = f2bf(xv);
      U[xb + r*RS + c2]       = h;
      U[xb + PLN + r*RS + c2] = f2bf(xv - bf2f(h));
      if ((i + 2) < T_STEPS) xv = x[(size_t)((i+2)*BATCH + b0r + r)*64 + c2];
    }
    __syncthreads();   // B3

    // ---- projection (layer3 waves) ----
    if (layer == 3 && l3act){
      f32x4 a1 = (f32x4){bav, bav, bav, bav};
      #pragma unroll
      for (int ks = 0; ks < 3; ++ks){
        const int base = sel8 ? PBB + l15*RS : ZROW;
        const int ih = base + hi*8 + ks*32;
        const int il = sel8 ? ih + PLN : ih;
        bf16x8 ah = *(const bf16x8*)(U + ih);
        bf16x8 al = *(const bf16x8*)(U + il);
        a1 = __builtin_amdgcn_mfma_f32_16x16x32_bf16(ah, phi[ks], a1, 0, 0, 0);
        a1 = __builtin_amdgcn_mfma_f32_16x16x32_bf16(al, phi[ks], a1, 0, 0, 0);
        a1 = __builtin_amdgcn_mfma_f32_16x16x32_bf16(ah, plo[ks], a1, 0, 0, 0);
      }
      if (hi < 2){
        const int s = i - 3;
        #pragma unroll
        for (int k = 0; k < 4; ++k)
          y_out[(size_t)(s*BATCH + b0r + hi*4 + k)*64 + ocol] = a1[k];
      }
    }
  }
}

extern "C" void kernel_launch(void* const* d_in, const int* in_sizes, int n_in,
                              void* d_out, int out_size, void* d_ws, size_t ws_size,
                              hipStream_t stream) {
  (void)in_sizes; (void)n_in; (void)out_size; (void)d_ws; (void)ws_size;
  const float* x  = (const float*)d_in[0];
  const float* W0 = (const float*)d_in[1];
  const float* b0 = (const float*)d_in[2];
  const float* W1 = (const float*)d_in[3];
  const float* b1 = (const float*)d_in[4];
  const float* W2 = (const float*)d_in[5];
  const float* b2 = (const float*)d_in[6];
  const float* W3 = (const float*)d_in[7];
  const float* b3 = (const float*)d_in[8];
  const float* Wa = (const float*)d_in[9];
  const float* ba = (const float*)d_in[10];
  float* out = (float*)d_out;

  hipLaunchKernelGGL(rnn_all, dim3(NBLK), dim3(1024), 0, stream,
                     x, W0, b0, W1, b1, W2, b2, W3, b3, Wa, ba, out);
}

// Round 15
// 2087.717 us; speedup vs baseline: 10.2662x; 10.2662x over previous
//
#include <hip/hip_runtime.h>

typedef unsigned int uint;
typedef unsigned short ushort;
typedef unsigned long long u64;
typedef __attribute__((ext_vector_type(8))) short bf16x8;
typedef __attribute__((ext_vector_type(4))) float f32x4;

// Problem constants
#define T_STEPS 512
#define BATCH   512
#define NB      8        // batch rows per replica
#define XS      104      // xi plane row stride (ushort) - input cols only
#define HS      40       // h ring row stride (ushort)
#define HSLOT   (16*HS)  // h ring slot stride (16 rows, rows 8-15 stay zero)
#define CSTR    12       // c-ring pad: floats per (slot,sidx) row
#define OUTC    96
#define FSTR    32       // flag stride in uints (128B line per flag)
#define NITER   256      // 2 steps per iteration

__device__ __forceinline__ ushort f2bf(float f){
  uint u = __builtin_bit_cast(uint, f);
  u = (u + 0x7FFFu + ((u >> 16) & 1u)) >> 16;   // RNE
  return (ushort)u;
}
__device__ __forceinline__ float bf2f(ushort h){
  uint u = ((uint)h) << 16; return __builtin_bit_cast(float, u);
}
__device__ __forceinline__ float sigm(float x){
  float e = __builtin_exp2f(-1.44269504f * x);
  return __builtin_amdgcn_rcpf(1.0f + e);
}
__device__ __forceinline__ float tanh_fast(float x){
  float e = __builtin_exp2f(-2.88539008f * x);
  return 2.0f * __builtin_amdgcn_rcpf(1.0f + e) - 1.0f;
}
// Flag ops: relaxed agent-scope atomics (LLC-coherent, no cache maintenance).
__device__ __forceinline__ uint aload32(const uint* p){
  return __hip_atomic_load(p, __ATOMIC_RELAXED, __HIP_MEMORY_SCOPE_AGENT);
}
__device__ __forceinline__ void astore32(uint* p, uint v){
  __hip_atomic_store(p, v, __ATOMIC_RELAXED, __HIP_MEMORY_SCOPE_AGENT);
}
__device__ __forceinline__ void astore64(u64* p, u64 v){
  __hip_atomic_store(p, v, __ATOMIC_RELAXED, __HIP_MEMORY_SCOPE_AGENT);
}
// ASYNC hop-data load: raw sc0 sc1 load, NO embedded wait. The value is NOT
// valid until an explicit `s_waitcnt vmcnt(0)` executes (compiler does not
// track asm-internal loads). Every use site is preceded by one.
__device__ __forceinline__ u64 aload64a(const u64* p){
  u64 v;
  asm volatile("global_load_dwordx2 %0, %1, off sc0 sc1" : "=v"(v) : "v"(p));
  return v;
}
#define VM_DRAIN() do { \
  asm volatile("s_waitcnt vmcnt(0)" ::: "memory"); \
  __builtin_amdgcn_sched_barrier(0); \
} while (0)

// 4-stage pipeline (stage = blockIdx.x>>6, rep = blockIdx.x&63), NB=8 rows.
// TWO time-steps fused per iteration. r15 change: hop payload loads are issued
// as raw async sc0sc1 loads (no compiler/atomic serialization possible) and
// retired by ONE explicit vmcnt(0) at the top of the NEXT iteration — a full
// iteration of hide window. That drain also retires old hop stores (lag-2
// producer publish stays proven). Blocking polls sleep longer (bounded traffic).
__global__ __launch_bounds__(512, 1)
void rnn_pipeline(const float* __restrict__ x,
                  const float* __restrict__ W0, const float* __restrict__ b0,
                  const float* __restrict__ W1, const float* __restrict__ b1,
                  const float* __restrict__ W2, const float* __restrict__ b2,
                  const float* __restrict__ W3, const float* __restrict__ b3,
                  const float* __restrict__ Wa, const float* __restrict__ ba,
                  float* __restrict__ y_out,
                  uint* __restrict__ prod, uint* __restrict__ consA,
                  uint* __restrict__ consB,
                  u64* __restrict__ hop0, u64* __restrict__ hop1,
                  u64* __restrict__ hop2, int rd)
{
  const int tid  = threadIdx.x;
  const int wv   = tid >> 6;      // wave 0..7
  const int lane = tid & 63;
  const int l15  = lane & 15;
  const int hi   = lane >> 4;     // 0..3
  const int rep  = blockIdx.x & 63;
  const int stage= blockIdx.x >> 6;
  const int b0r  = rep * NB;
  const int rmask= rd - 1;

  const int dil = (stage==0)?1:(stage==1)?3:(stage==2)?6:12;
  const int KIN = (stage==0)?64:96;
  const int K   = KIN + 64;
  const int nin = KIN >> 5;
  const float* Wl = (stage==0)?W0:(stage==1)?W1:(stage==2)?W2:W3;
  const float* bl = (stage==0)?b0:(stage==1)?b1:(stage==2)?b2:b3;

  __shared__ __align__(16) ushort xiA_hi[16*XS], xiA_lo[16*XS];  // step t input
  __shared__ __align__(16) ushort xiB_hi[16*XS], xiB_lo[16*XS];  // step u input
  __shared__ __align__(16) float  sh_c[12*128*CSTR];             // c ring
  __shared__ __align__(16) ushort h_hi[12*HSLOT], h_lo[12*HSLOT];// h ring (16 rows)
  __shared__ __align__(16) ushort outpA[2304], outpB[2304];      // hop payloads
  __shared__ __align__(16) ushort o1pA[1536], o1pB[1536];        // stage3 out1
  __shared__ __align__(16) float  o3fA[768],  o3fB[768];         // stage3 out3

  for (int i = tid; i < 16*XS; i += 512){ xiA_hi[i]=0; xiA_lo[i]=0; xiB_hi[i]=0; xiB_lo[i]=0; }
  for (int i = tid; i < 12*128*CSTR; i += 512) sh_c[i] = 0.0f;
  for (int i = tid; i < 12*HSLOT; i += 512){ h_hi[i]=0; h_lo[i]=0; }
  for (int i = tid; i < 2304; i += 512){ outpA[i]=0; outpB[i]=0; }
  for (int i = tid; i < 1536; i += 512){ o1pA[i]=0; o1pB[i]=0; }
  for (int i = tid; i < 768; i += 512){ o3fA[i]=0.0f; o3fB[i]=0.0f; }

  const int sidx = 16*wv + l15;  // state index 0..127 owned by this lane

  // Layer weights as split-bf16 MFMA B-fragments (zero-padded past K).
  bf16x8 whi[4][5], wlo[4][5];
  #pragma unroll
  for (int j = 0; j < 4; ++j){
    const int grow = 128*j + sidx;
    #pragma unroll
    for (int ks = 0; ks < 5; ++ks){
      bf16x8 vh, vl;
      const int cb = ks*32 + hi*8;
      if (cb < K){
        const float* p = Wl + (size_t)grow*K + cb;
        #pragma unroll
        for (int q = 0; q < 8; ++q){
          float w = p[q];
          ushort h = f2bf(w);
          vh[q] = (short)h;
          vl[q] = (short)f2bf(w - bf2f(h));
        }
      } else {
        #pragma unroll
        for (int q = 0; q < 8; ++q){ vh[q] = 0; vl[q] = 0; }
      }
      whi[j][ks] = vh; wlo[j][ks] = vl;
    }
  }
  float bias[4];
  #pragma unroll
  for (int j = 0; j < 4; ++j) bias[j] = bl[128*j + sidx];

  // Projection weights (stage3, waves 0..3)
  bf16x8 phi[3], plo[3];
  #pragma unroll
  for (int ks = 0; ks < 3; ++ks){
    bf16x8 z;
    #pragma unroll
    for (int q = 0; q < 8; ++q) z[q]=0;
    phi[ks]=z; plo[ks]=z;
  }
  float bav = 0.0f;
  if (stage == 3 && wv < 4){
    const int ocol = 16*wv + l15;
    #pragma unroll
    for (int ks = 0; ks < 3; ++ks){
      const float* p = Wa + (size_t)ocol*96 + ks*32 + hi*8;
      bf16x8 vh, vl;
      #pragma unroll
      for (int q = 0; q < 8; ++q){
        float w = p[q];
        ushort h = f2bf(w);
        vh[q] = (short)h;
        vl[q] = (short)f2bf(w - bf2f(h));
      }
      phi[ks] = vh; plo[ks] = vl;
    }
    bav = ba[ocol];
  }

  // Flag wiring (each flag on its own 128B line)
  uint* up_prod  = (stage==1)? &prod[rep*FSTR] : (stage==2)? &prod[(64+rep)*FSTR] :
                   (stage==3)? &prod[(128+rep)*FSTR] : nullptr;
  uint* up_prod1 = (stage==3)? &prod[(64+rep)*FSTR] : nullptr;
  uint* my_prod  = (stage==0)? &prod[rep*FSTR] : (stage==1)? &prod[(64+rep)*FSTR] :
                   (stage==2)? &prod[(128+rep)*FSTR] : nullptr;
  uint* my_consA = (stage==1)? &consA[rep*FSTR] : (stage==2)? &consA[(64+rep)*FSTR] :
                   (stage==3)? &consA[(128+rep)*FSTR] : nullptr;
  uint* my_consB = (stage==3)? &consB[rep*FSTR] : nullptr;
  uint* dnA      = (stage==0)? &consA[rep*FSTR] : (stage==1)? &consA[(64+rep)*FSTR] :
                   (stage==2)? &consA[(128+rep)*FSTR] : nullptr;
  uint* dnB      = (stage==1)? &consB[rep*FSTR] : nullptr;
  const u64* hop_in  = (stage==1)? hop0 : (stage==2)? hop1 : nullptr;
  u64*       hop_out = (stage==0)? hop0 : (stage==1)? hop1 : (stage==2)? hop2 : nullptr;

  // GEMM: input-ks from xi planes, h-ks direct from h-ring slots.
  const int ax = l15*XS + hi*8;
  const int ah = l15*HS + hi*8;
  auto gemm = [&](const ushort* xhi, const ushort* xlo, int pslot, int dslot,
                  f32x4 acc[4]){
    #pragma unroll
    for (int ks = 0; ks < 5; ++ks){
      if (ks*32 < K){
        const ushort *ph, *pl; int off;
        if (ks < nin){ ph = xhi; pl = xlo; off = ax + ks*32; }
        else if (ks == nin){ ph = h_hi; pl = h_lo; off = pslot*HSLOT + ah; }
        else { ph = h_hi; pl = h_lo; off = dslot*HSLOT + ah; }
        bf16x8 a_hi = *(const bf16x8*)(ph + off);
        bf16x8 a_lo = *(const bf16x8*)(pl + off);
        #pragma unroll
        for (int j = 0; j < 4; ++j){
          acc[j] = __builtin_amdgcn_mfma_f32_16x16x32_bf16(a_hi, whi[j][ks], acc[j], 0, 0, 0);
          acc[j] = __builtin_amdgcn_mfma_f32_16x16x32_bf16(a_lo, whi[j][ks], acc[j], 0, 0, 0);
          acc[j] = __builtin_amdgcn_mfma_f32_16x16x32_bf16(a_hi, wlo[j][ks], acc[j], 0, 0, 0);
        }
      }
    }
  };
  auto gates = [&](const f32x4 acc[4], f32x4 pc, int cslot, bool has_prev,
                   bool has_del, ushort* outp, float* o3, f32x4& ncv_out){
    f32x4 dc;
    if (dil == 1) dc = pc;
    else dc = *(const f32x4*)(sh_c + cslot*(128*CSTR) + sidx*CSTR + (hi&1)*4);
    float whv[4];
    #pragma unroll
    for (int k = 0; k < 4; ++k){
      float f  = sigm(acc[0][k] + 1.0f);
      float cd = tanh_fast(acc[1][k]);
      float al = sigm(acc[2][k]);
      float og = sigm(acc[3][k]);
      float wt = has_del ? (al*pc[k] + (1.0f - al)*dc[k]) : pc[k];
      float nc = has_prev ? (f*wt + (1.0f - f)*cd) : cd;
      ncv_out[k] = nc;
      whv[k] = og * nc;
    }
    if (hi < 2){
      *(f32x4*)(sh_c + cslot*(128*CSTR) + sidx*CSTR + hi*4) = ncv_out;
      #pragma unroll
      for (int k = 0; k < 4; ++k){
        const int r = hi*4 + k;
        const float w = whv[k];
        if (sidx < OUTC){
          if (stage == 3){
            o3[r*OUTC + sidx] = w;
          } else {
            ushort hb = f2bf(w);
            outp[r*OUTC + sidx]       = hb;
            outp[768 + r*OUTC + sidx] = f2bf(w - bf2f(hb));
          }
        } else {
          ushort hb = f2bf(w);
          h_hi[cslot*HSLOT + r*HS + (sidx - OUTC)] = hb;
          h_lo[cslot*HSLOT + r*HS + (sidx - OUTC)] = f2bf(w - bf2f(hb));
        }
      }
    }
  };
  auto proj = [&](const ushort* outp, int s){
    if (wv < 4){
      f32x4 a1 = (f32x4){bav, bav, bav, bav};
      const int pbase = l15*96 + hi*8;
      #pragma unroll
      for (int ks = 0; ks < 3; ++ks){
        bf16x8 a_hi = *(const bf16x8*)(outp + pbase + ks*32);
        bf16x8 a_lo = *(const bf16x8*)(outp + 768 + pbase + ks*32);
        a1 = __builtin_amdgcn_mfma_f32_16x16x32_bf16(a_hi, phi[ks], a1, 0, 0, 0);
        a1 = __builtin_amdgcn_mfma_f32_16x16x32_bf16(a_lo, phi[ks], a1, 0, 0, 0);
        a1 = __builtin_amdgcn_mfma_f32_16x16x32_bf16(a_hi, plo[ks], a1, 0, 0, 0);
      }
      if (hi < 2){
        const int ocol = 16*wv + l15;
        #pragma unroll
        for (int k = 0; k < 4; ++k)
          y_out[(size_t)(s*BATCH + b0r + hi*4 + k)*64 + ocol] = a1[k];
      }
    }
  };

  __syncthreads();

  // ---- preloop: block until producer >= 4, issue iteration-0 loads (async) ----
  u64 pfA_t = 0, pfA_u = 0, pfC_t = 0, pfC_u = 0;
  float xv_t = 0.0f, xv_u = 0.0f;
  uint fvU = 0, fvU1 = 0, fvDA = 0, fvDB = 0;
  if (stage == 0){
    xv_t = x[(size_t)(b0r + (tid>>6))*64 + (tid&63)];
    xv_u = x[(size_t)(BATCH + b0r + (tid>>6))*64 + (tid&63)];
  } else if (stage < 3){
    do { fvU = aload32(up_prod); if (fvU < 4u) __builtin_amdgcn_s_sleep(16); } while (fvU < 4u);
    if (tid < 384){
      pfA_t = aload64a(hop_in + (size_t)rep*384 + tid);
      pfA_u = aload64a(hop_in + (size_t)(64 + rep)*384 + tid);
    }
  } else {
    do { fvU  = aload32(up_prod);  if (fvU  < 4u) __builtin_amdgcn_s_sleep(16); } while (fvU  < 4u);
    do { fvU1 = aload32(up_prod1); if (fvU1 < 4u) __builtin_amdgcn_s_sleep(16); } while (fvU1 < 4u);
    if (tid < 384){
      pfA_t = aload64a(hop2 + (size_t)rep*384 + tid);
      pfA_u = aload64a(hop2 + (size_t)(64 + rep)*384 + tid);
      pfC_t = aload64a(hop1 + (size_t)rep*384 + tid);
      pfC_u = aload64a(hop1 + (size_t)(64 + rep)*384 + tid);
    }
  }

  f32x4 ncv_prev = (f32x4){0.0f, 0.0f, 0.0f, 0.0f};
  int cur_t = 0, prv_t = dil - 1;

  for (int it = 0; it < NITER; ++it){
    const int t = 2*it, u = t + 1;
    const int slot_t = t & rmask, slot_u = u & rmask;
    const int cur_u = (cur_t + 1 == dil) ? 0 : cur_t + 1;
    const int del_t = (t >= dil) ? cur_t : prv_t;
    const int del_u = (u >= dil) ? cur_u : cur_t;

    // ---- retire last iteration's async loads + old hop stores (ONE wait) ----
    VM_DRAIN();

    // ---- upstream optimistic check (sample is 1 iteration old) ----
    if (stage > 0){
      const bool bad = (fvU < (uint)(t+4)) || (stage == 3 && fvU1 < (uint)(t+4));
      if (bad){
        if (lane == 0){
          while (aload32(up_prod) < (uint)(t+2)) __builtin_amdgcn_s_sleep(16);
          if (stage == 3)
            while (aload32(up_prod1) < (uint)(t+2)) __builtin_amdgcn_s_sleep(16);
        }
        if (tid < 384){
          if (stage < 3){
            pfA_t = aload64a(hop_in + (size_t)(slot_t*64 + rep)*384 + tid);
            pfA_u = aload64a(hop_in + (size_t)(slot_u*64 + rep)*384 + tid);
          } else {
            pfA_t = aload64a(hop2 + (size_t)(slot_t*64 + rep)*384 + tid);
            pfA_u = aload64a(hop2 + (size_t)(slot_u*64 + rep)*384 + tid);
            pfC_t = aload64a(hop1 + (size_t)(slot_t*64 + rep)*384 + tid);
            pfC_u = aload64a(hop1 + (size_t)(slot_u*64 + rep)*384 + tid);
          }
        }
        VM_DRAIN();   // reload path: values must be valid before staging
      }
    }
    // ---- stage both steps' inputs ----
    if (stage == 0){
      const int r = tid >> 6, c = tid & 63;
      ushort hb = f2bf(xv_t);
      xiA_hi[r*XS + c] = hb; xiA_lo[r*XS + c] = f2bf(xv_t - bf2f(hb));
      hb = f2bf(xv_u);
      xiB_hi[r*XS + c] = hb; xiB_lo[r*XS + c] = f2bf(xv_u - bf2f(hb));
    } else {
      if (tid < 384){
        const int q = (tid < 192) ? tid : tid - 192;
        const int off = (q/24)*XS + (q%24)*4;
        ushort* plA = (tid < 192) ? xiA_hi : xiA_lo;
        ushort* plB = (tid < 192) ? xiB_hi : xiB_lo;
        *(u64*)(plA + off) = pfA_t;
        *(u64*)(plB + off) = pfA_u;
        if (stage == 3){
          *(u64*)(o1pA + 4*tid) = pfC_t;
          *(u64*)(o1pB + 4*tid) = pfC_u;
        }
      }
    }
    __syncthreads();   // B1
    if (tid == 0){
      if (stage > 0){
        astore32(my_consA, (uint)(t+2));
        if (stage == 3) astore32(my_consB, (uint)(t+2));
      }
      if (stage < 3 && it >= 2) astore32(my_prod, (uint)(t-2));  // lag-2 proof
    }
    // ---- downstream-full check (optimistic; blocking fallback) ----
    if (stage < 3 && u >= rd){
      const bool badc = (fvDA < (uint)(t+4-rd)) || (stage == 1 && fvDB < (uint)(t+4-rd));
      if (badc && lane == 0){
        while (aload32(dnA) < (uint)(t+2-rd)) __builtin_amdgcn_s_sleep(16);
        if (stage == 1)
          while (aload32(dnB) < (uint)(t+2-rd)) __builtin_amdgcn_s_sleep(16);
      }
    }
    // ---- issue ASYNC prefetch for next iteration (retired at next VM_DRAIN) ----
    if (it + 1 < NITER){
      const int nt = (t+2) & rmask, nu = (t+3) & rmask;
      if (stage == 0){
        xv_t = x[(size_t)((t+2)*BATCH + b0r + (tid>>6))*64 + (tid&63)];
        xv_u = x[(size_t)((t+3)*BATCH + b0r + (tid>>6))*64 + (tid&63)];
      } else if (stage < 3){
        if (tid < 384){
          pfA_t = aload64a(hop_in + (size_t)(nt*64 + rep)*384 + tid);
          pfA_u = aload64a(hop_in + (size_t)(nu*64 + rep)*384 + tid);
        }
        fvU = aload32(up_prod);
      } else {
        if (tid < 384){
          pfA_t = aload64a(hop2 + (size_t)(nt*64 + rep)*384 + tid);
          pfA_u = aload64a(hop2 + (size_t)(nu*64 + rep)*384 + tid);
          pfC_t = aload64a(hop1 + (size_t)(nt*64 + rep)*384 + tid);
          pfC_u = aload64a(hop1 + (size_t)(nu*64 + rep)*384 + tid);
        }
        fvU  = aload32(up_prod);
        fvU1 = aload32(up_prod1);
      }
    }
    if (stage < 3) fvDA = aload32(dnA);
    if (stage == 1) fvDB = aload32(dnB);
    asm volatile("" ::: "memory");

    // ---- STEP t ----
    f32x4 acc[4];
    #pragma unroll
    for (int j = 0; j < 4; ++j) acc[j] = (f32x4){bias[j],bias[j],bias[j],bias[j]};
    gemm(xiA_hi, xiA_lo, prv_t, del_t, acc);
    f32x4 ncv;
    gates(acc, ncv_prev, cur_t, (t >= 1), (t >= dil), outpA, o3fA, ncv);
    ncv_prev = ncv;
    __syncthreads();   // Bmid

    if (stage == 3){
      for (int j = tid; j < 768; j += 512){
        float v = o3fA[j] + bf2f(o1pA[j]) + bf2f(o1pA[768 + j]);
        ushort hb = f2bf(v);
        outpA[j]       = hb;
        outpA[768 + j] = f2bf(v - bf2f(hb));
      }
    }
    // ---- STEP u ----
    #pragma unroll
    for (int j = 0; j < 4; ++j) acc[j] = (f32x4){bias[j],bias[j],bias[j],bias[j]};
    gemm(xiB_hi, xiB_lo, cur_t, del_u, acc);
    gates(acc, ncv_prev, cur_u, true, (u >= dil), outpB, o3fB, ncv);
    ncv_prev = ncv;
    __syncthreads();   // B2

    if (stage < 3){
      if (tid < 384){
        astore64(hop_out + (size_t)(slot_t*64 + rep)*384 + tid, *(const u64*)(outpA + 4*tid));
        astore64(hop_out + (size_t)(slot_u*64 + rep)*384 + tid, *(const u64*)(outpB + 4*tid));
      }
    } else {
      proj(outpA, t);   // outpA stable after B2
      for (int j = tid; j < 768; j += 512){
        float v = o3fB[j] + bf2f(o1pB[j]) + bf2f(o1pB[768 + j]);
        ushort hb = f2bf(v);
        outpB[j]       = hb;
        outpB[768 + j] = f2bf(v - bf2f(hb));
      }
      __syncthreads(); // B3u
      proj(outpB, u);
    }
    prv_t = cur_u;
    cur_t = (cur_u + 1 == dil) ? 0 : cur_u + 1;
  }

  // ---- postloop: drain all stores, terminal flags ----
  asm volatile("s_waitcnt vmcnt(0)" ::: "memory");
  __syncthreads();
  if (stage < 3 && tid == 0) astore32(my_prod, (uint)(T_STEPS + 8));
}

extern "C" void kernel_launch(void* const* d_in, const int* in_sizes, int n_in,
                              void* d_out, int out_size, void* d_ws, size_t ws_size,
                              hipStream_t stream) {
  (void)in_sizes; (void)n_in; (void)out_size;
  const float* x  = (const float*)d_in[0];
  const float* W0 = (const float*)d_in[1];
  const float* b0 = (const float*)d_in[2];
  const float* W1 = (const float*)d_in[3];
  const float* b1 = (const float*)d_in[4];
  const float* W2 = (const float*)d_in[5];
  const float* b2 = (const float*)d_in[6];
  const float* W3 = (const float*)d_in[7];
  const float* b3 = (const float*)d_in[8];
  const float* Wa = (const float*)d_in[9];
  const float* ba = (const float*)d_in[10];
  float* out = (float*)d_out;

  // Ring depth: largest power of 2 (<= 512) whose rings fit in d_ws.
  int rd = 16;
  if (ws_size > 65536){
    size_t avail = ws_size - 65536;
    while (rd < 512 && (size_t)(rd * 2) * 64 * 9216 <= avail) rd *= 2;
  }

  // Flags: 128B line each. prod[3][64] @0, consA[3][64] @24576, consB[64] @49152.
  uint* prod  = (uint*)d_ws;
  uint* consA = (uint*)((char*)d_ws + 24576);
  uint* consB = (uint*)((char*)d_ws + 49152);
  u64* hop0 = (u64*)((char*)d_ws + 65536);   // [rd][64][384] u64 (hi/lo planes)
  u64* hop1 = hop0 + (size_t)rd*64*384;
  u64* hop2 = hop1 + (size_t)rd*64*384;

  hipMemsetAsync(d_ws, 0, 65536, stream);  // re-zero flags every call
  hipLaunchKernelGGL(rnn_pipeline, dim3(256), dim3(512), 0, stream,
                     x, W0, b0, W1, b1, W2, b2, W3, b3, Wa, ba,
                     out, prod, consA, consB, hop0, hop1, hop2, rd);
}